// Round 1
// baseline (2431.198 us; speedup 1.0000x reference)
//
#include <hip/hip_runtime.h>
#include <math.h>

// Problem constants
constexpr int Dm  = 1024;
constexpr int Hh  = 16;
constexpr int HDm = 64;
constexpr int FFm = 4096;
constexpr int Bb  = 2;
constexpr int Sq  = 2048;
constexpr int Mm  = Bb * Sq;   // 4096 rows

// ---------------------------------------------------------------------------
// Fused QKV projection: out[b,h,s,e] = sum_d x[b,s,d] * W[h,d,e] + bias[h,e]
// grid (Mm/64, H, 3)  block 256.  64x64 tile, K=1024 in steps of 16.
// ---------------------------------------------------------------------------
__global__ __launch_bounds__(256) void qkv_gemm(
    const float* __restrict__ x,
    const float* __restrict__ Wq, const float* __restrict__ bq,
    const float* __restrict__ Wk, const float* __restrict__ bk,
    const float* __restrict__ Wv, const float* __restrict__ bv,
    float* __restrict__ qo, float* __restrict__ ko, float* __restrict__ vo)
{
    const int mt = blockIdx.x, h = blockIdx.y, which = blockIdx.z;
    const float* W    = (which == 0) ? Wq : (which == 1) ? Wk : Wv;
    const float* bias = (which == 0) ? bq : (which == 1) ? bk : bv;
    float* out        = (which == 0) ? qo : (which == 1) ? ko : vo;
    const float* Wh = W + (size_t)h * Dm * HDm;   // D x 64 row-major
    const float* bh = bias + h * HDm;

    const int tid = threadIdx.x;
    const int tx = tid & 15, ty = tid >> 4;
    __shared__ float As[16][68];   // [k][m] transposed
    __shared__ float Bs[16][68];   // [k][n]
    float acc[4][4] = {};
    const int m0 = mt * 64;

    for (int k0 = 0; k0 < Dm; k0 += 16) {
        #pragma unroll
        for (int r = 0; r < 4; ++r) {               // A tile 64x16
            int e = tid + 256 * r;
            int row = e >> 4, col = e & 15;
            As[col][row] = x[(size_t)(m0 + row) * Dm + k0 + col];
        }
        #pragma unroll
        for (int r = 0; r < 4; ++r) {               // B tile 16x64
            int e = tid + 256 * r;
            int row = e >> 6, col = e & 63;
            Bs[row][col] = Wh[(size_t)(k0 + row) * HDm + col];
        }
        __syncthreads();
        #pragma unroll
        for (int kk = 0; kk < 16; ++kk) {
            float4 a4 = *(const float4*)&As[kk][ty * 4];
            float4 b4 = *(const float4*)&Bs[kk][tx * 4];
            float av[4] = {a4.x, a4.y, a4.z, a4.w};
            float bv4[4] = {b4.x, b4.y, b4.z, b4.w};
            #pragma unroll
            for (int i = 0; i < 4; ++i)
                #pragma unroll
                for (int j = 0; j < 4; ++j)
                    acc[i][j] += av[i] * bv4[j];
        }
        __syncthreads();
    }
    // epilogue -> [B,H,S,HD]
    #pragma unroll
    for (int i = 0; i < 4; ++i) {
        int m = m0 + ty * 4 + i;
        int bbi = m >> 11, ss = m & 2047;
        size_t o = (((size_t)bbi * Hh + h) * Sq + ss) * HDm + tx * 4;
        float4 w;
        w.x = acc[i][0] + bh[tx * 4 + 0];
        w.y = acc[i][1] + bh[tx * 4 + 1];
        w.z = acc[i][2] + bh[tx * 4 + 2];
        w.w = acc[i][3] + bh[tx * 4 + 3];
        *(float4*)&out[o] = w;
    }
}

// ---------------------------------------------------------------------------
// Flash attention f32 (faithful 1/HD scale, causal).
// grid (S/64, H, B), block 256.  64-query x 64-key tiles, online softmax.
// ctx written as [B,S,H*HD] (row-major D) so ctx @ Wo is a standard GEMM.
// ---------------------------------------------------------------------------
__global__ __launch_bounds__(256) void attn_kernel(
    const float* __restrict__ q, const float* __restrict__ k,
    const float* __restrict__ v, float* __restrict__ ctx)
{
    const int qt = blockIdx.x, h = blockIdx.y, b = blockIdx.z;
    const int tid = threadIdx.x;
    const int tx = tid & 15, ty = tid >> 4;

    __shared__ float Qs[64][68];
    __shared__ float Ks[64][68];
    __shared__ float Vs[64][68];
    __shared__ float Ps[64][65];

    const size_t bh_base = ((size_t)b * Hh + h) * Sq * HDm;
    const float SCALE = 1.0f / 64.0f;   // reference divides scores by HD

    // load Q tile, pre-scaled
    #pragma unroll
    for (int r = 0; r < 4; ++r) {
        int e = tid + 256 * r;          // float4 index
        int row = e >> 4, c4 = (e & 15) * 4;
        float4 t4 = *(const float4*)&q[bh_base + (size_t)(qt * 64 + row) * HDm + c4];
        t4.x *= SCALE; t4.y *= SCALE; t4.z *= SCALE; t4.w *= SCALE;
        *(float4*)&Qs[row][c4] = t4;
    }

    float acc[4][4] = {};
    float m_reg[4], l_reg[4];
    #pragma unroll
    for (int i = 0; i < 4; ++i) { m_reg[i] = -1e30f; l_reg[i] = 0.0f; }

    for (int kt = 0; kt <= qt; ++kt) {
        __syncthreads();   // prev PV done; Qs visible on first iter
        #pragma unroll
        for (int r = 0; r < 4; ++r) {
            int e = tid + 256 * r;
            int row = e >> 4, c4 = (e & 15) * 4;
            size_t go = bh_base + (size_t)(kt * 64 + row) * HDm + c4;
            *(float4*)&Ks[row][c4] = *(const float4*)&k[go];
            *(float4*)&Vs[row][c4] = *(const float4*)&v[go];
        }
        __syncthreads();

        // S tile: rows ty*4+i (queries), cols tx*4+j (keys)
        float sreg[4][4] = {};
        #pragma unroll
        for (int d0 = 0; d0 < 16; ++d0) {
            float4 q4[4], k4[4];
            #pragma unroll
            for (int i = 0; i < 4; ++i) q4[i] = *(const float4*)&Qs[ty * 4 + i][d0 * 4];
            #pragma unroll
            for (int j = 0; j < 4; ++j) k4[j] = *(const float4*)&Ks[tx * 4 + j][d0 * 4];
            #pragma unroll
            for (int i = 0; i < 4; ++i)
                #pragma unroll
                for (int j = 0; j < 4; ++j)
                    sreg[i][j] += q4[i].x * k4[j].x + q4[i].y * k4[j].y
                                + q4[i].z * k4[j].z + q4[i].w * k4[j].w;
        }
        // causal mask on diagonal tile
        if (kt == qt) {
            #pragma unroll
            for (int i = 0; i < 4; ++i)
                #pragma unroll
                for (int j = 0; j < 4; ++j)
                    if ((tx * 4 + j) > (ty * 4 + i)) sreg[i][j] = -1e30f;
        }

        // online softmax, stats replicated across the 16-lane row group
        #pragma unroll
        for (int i = 0; i < 4; ++i) {
            float tmax = fmaxf(fmaxf(sreg[i][0], sreg[i][1]),
                               fmaxf(sreg[i][2], sreg[i][3]));
            #pragma unroll
            for (int o = 1; o < 16; o <<= 1)
                tmax = fmaxf(tmax, __shfl_xor(tmax, o));
            float mold = m_reg[i];
            float mnew = fmaxf(mold, tmax);
            float cf = __expf(mold - mnew);
            m_reg[i] = mnew;
            float psum = 0.0f;
            #pragma unroll
            for (int j = 0; j < 4; ++j) {
                float p = __expf(sreg[i][j] - mnew);
                Ps[ty * 4 + i][tx * 4 + j] = p;
                psum += p;
            }
            #pragma unroll
            for (int o = 1; o < 16; o <<= 1)
                psum += __shfl_xor(psum, o);
            l_reg[i] = l_reg[i] * cf + psum;
            #pragma unroll
            for (int j = 0; j < 4; ++j) acc[i][j] *= cf;
        }
        __syncthreads();   // Ps ready

        // PV: acc[i][j] += sum_t P[row_i][t] * V[t][col_j]
        #pragma unroll 8
        for (int t = 0; t < 64; ++t) {
            float4 v4 = *(const float4*)&Vs[t][tx * 4];
            #pragma unroll
            for (int i = 0; i < 4; ++i) {
                float p = Ps[ty * 4 + i][t];
                acc[i][0] += p * v4.x;
                acc[i][1] += p * v4.y;
                acc[i][2] += p * v4.z;
                acc[i][3] += p * v4.w;
            }
        }
    }

    // epilogue: normalize and write ctx[b, s, h*64 + d]
    #pragma unroll
    for (int i = 0; i < 4; ++i) {
        float inv = 1.0f / l_reg[i];
        int sg = qt * 64 + ty * 4 + i;
        size_t o = ((size_t)b * Sq + sg) * Dm + h * HDm + tx * 4;
        float4 w = make_float4(acc[i][0] * inv, acc[i][1] * inv,
                               acc[i][2] * inv, acc[i][3] * inv);
        *(float4*)&ctx[o] = w;
    }
}

// ---------------------------------------------------------------------------
// Generic tiled GEMM: out = A[M,K] @ Bw[K,N] + bias (+ res) (gelu optional)
// grid (M/64, N/64), block 256.
// ---------------------------------------------------------------------------
template<int GELU, int RES>
__global__ __launch_bounds__(256) void gemm64(
    const float* __restrict__ A, const float* __restrict__ Bw,
    const float* __restrict__ bias, const float* __restrict__ res,
    float* __restrict__ out, int K, int N)
{
    const int mt = blockIdx.x, nt = blockIdx.y;
    const int tid = threadIdx.x;
    const int tx = tid & 15, ty = tid >> 4;
    __shared__ float As[16][68];
    __shared__ float Bs[16][68];
    float acc[4][4] = {};
    const int m0 = mt * 64, n0 = nt * 64;

    for (int k0 = 0; k0 < K; k0 += 16) {
        #pragma unroll
        for (int r = 0; r < 4; ++r) {
            int e = tid + 256 * r;
            int row = e >> 4, col = e & 15;
            As[col][row] = A[(size_t)(m0 + row) * K + k0 + col];
        }
        #pragma unroll
        for (int r = 0; r < 4; ++r) {
            int e = tid + 256 * r;
            int row = e >> 6, col = e & 63;
            Bs[row][col] = Bw[(size_t)(k0 + row) * N + n0 + col];
        }
        __syncthreads();
        #pragma unroll
        for (int kk = 0; kk < 16; ++kk) {
            float4 a4 = *(const float4*)&As[kk][ty * 4];
            float4 b4 = *(const float4*)&Bs[kk][tx * 4];
            float av[4] = {a4.x, a4.y, a4.z, a4.w};
            float bv4[4] = {b4.x, b4.y, b4.z, b4.w};
            #pragma unroll
            for (int i = 0; i < 4; ++i)
                #pragma unroll
                for (int j = 0; j < 4; ++j)
                    acc[i][j] += av[i] * bv4[j];
        }
        __syncthreads();
    }
    #pragma unroll
    for (int i = 0; i < 4; ++i) {
        int m = m0 + ty * 4 + i;
        size_t ro = (size_t)m * N + n0 + tx * 4;
        #pragma unroll
        for (int j = 0; j < 4; ++j) {
            float val = acc[i][j] + bias[n0 + tx * 4 + j];
            if (RES) val += res[ro + j];
            if (GELU) val = 0.5f * val * (1.0f + erff(val * 0.70710678118654752f));
            out[ro + j] = val;
        }
    }
}

// ---------------------------------------------------------------------------
// Row LayerNorm: block per row (1024 elems), 256 threads x float4.
// ---------------------------------------------------------------------------
__global__ __launch_bounds__(256) void ln_kernel(
    const float* __restrict__ in, const float* __restrict__ g,
    const float* __restrict__ be, float* __restrict__ out)
{
    const int m = blockIdx.x;
    const int tid = threadIdx.x;
    const float4 vl = *(const float4*)&in[(size_t)m * Dm + tid * 4];
    float s  = vl.x + vl.y + vl.z + vl.w;
    float s2 = vl.x * vl.x + vl.y * vl.y + vl.z * vl.z + vl.w * vl.w;
    #pragma unroll
    for (int o = 32; o > 0; o >>= 1) {
        s  += __shfl_down(s, o);
        s2 += __shfl_down(s2, o);
    }
    __shared__ float rs[4], rs2[4];
    const int w = tid >> 6;
    if ((tid & 63) == 0) { rs[w] = s; rs2[w] = s2; }
    __syncthreads();
    s  = rs[0] + rs[1] + rs[2] + rs[3];
    s2 = rs2[0] + rs2[1] + rs2[2] + rs2[3];
    const float mean = s * (1.0f / Dm);
    const float var  = s2 * (1.0f / Dm) - mean * mean;
    const float rstd = rsqrtf(var + 1e-5f);
    const float4 gv = *(const float4*)&g[tid * 4];
    const float4 bv = *(const float4*)&be[tid * 4];
    float4 ov;
    ov.x = (vl.x - mean) * rstd * gv.x + bv.x;
    ov.y = (vl.y - mean) * rstd * gv.y + bv.y;
    ov.z = (vl.z - mean) * rstd * gv.z + bv.z;
    ov.w = (vl.w - mean) * rstd * gv.w + bv.w;
    *(float4*)&out[(size_t)m * Dm + tid * 4] = ov;
}

// ---------------------------------------------------------------------------
extern "C" void kernel_launch(void* const* d_in, const int* in_sizes, int n_in,
                              void* d_out, int out_size, void* d_ws, size_t ws_size,
                              hipStream_t stream)
{
    const float* x  = (const float*)d_in[0];
    const float* Wq = (const float*)d_in[1];
    const float* bq = (const float*)d_in[2];
    const float* Wk = (const float*)d_in[3];
    const float* bk = (const float*)d_in[4];
    const float* Wv = (const float*)d_in[5];
    const float* bv = (const float*)d_in[6];
    const float* Wo = (const float*)d_in[7];
    const float* bo = (const float*)d_in[8];
    const float* W1 = (const float*)d_in[9];
    const float* b1 = (const float*)d_in[10];
    const float* W2 = (const float*)d_in[11];
    const float* b2 = (const float*)d_in[12];
    const float* g1 = (const float*)d_in[13];
    const float* be1= (const float*)d_in[14];
    const float* g2 = (const float*)d_in[15];
    const float* be2= (const float*)d_in[16];
    float* out = (float*)d_out;

    char* ws = (char*)d_ws;
    const size_t SZ = (size_t)Mm * Dm * sizeof(float);   // 16.78 MB
    float* qb   = (float*)(ws + 0 * SZ);
    float* kb   = (float*)(ws + 1 * SZ);
    float* vb   = (float*)(ws + 2 * SZ);
    float* ctx  = (float*)(ws + 3 * SZ);
    float* y    = (float*)(ws + 4 * SZ);
    float* x1   = (float*)(ws + 5 * SZ);
    float* hbuf = (float*)(ws + 6 * SZ);                 // 4*SZ (B,S,FF)
    float* y2   = qb;                                    // reuse (q dead)

    qkv_gemm<<<dim3(Mm / 64, Hh, 3), 256, 0, stream>>>(
        x, Wq, bq, Wk, bk, Wv, bv, qb, kb, vb);
    attn_kernel<<<dim3(Sq / 64, Hh, Bb), 256, 0, stream>>>(qb, kb, vb, ctx);
    gemm64<0, 1><<<dim3(Mm / 64, Dm / 64), 256, 0, stream>>>(
        ctx, Wo, bo, x, y, Dm, Dm);
    ln_kernel<<<Mm, 256, 0, stream>>>(y, g1, be1, x1);
    gemm64<1, 0><<<dim3(Mm / 64, FFm / 64), 256, 0, stream>>>(
        x1, W1, b1, nullptr, hbuf, Dm, FFm);
    gemm64<0, 1><<<dim3(Mm / 64, Dm / 64), 256, 0, stream>>>(
        hbuf, W2, b2, x1, y2, FFm, Dm);
    ln_kernel<<<Mm, 256, 0, stream>>>(y2, g2, be2, out);
}

// Round 2
// 405.966 us; speedup vs baseline: 5.9887x; 5.9887x over previous
//
#include <hip/hip_runtime.h>
#include <math.h>

// Problem constants
constexpr int Dm  = 1024;
constexpr int Hh  = 16;
constexpr int HDm = 64;
constexpr int FFm = 4096;
constexpr int Bb  = 2;
constexpr int Sq  = 2048;
constexpr int Mm  = Bb * Sq;   // 4096 rows

typedef __attribute__((ext_vector_type(8))) short short8;
typedef __attribute__((ext_vector_type(4))) short short4v;
typedef __attribute__((ext_vector_type(4))) float f32x4;

__device__ __forceinline__ unsigned short f2b(float f) {
    union { float f; unsigned u; } v; v.f = f;
    unsigned r = v.u + 0x7FFFu + ((v.u >> 16) & 1u);   // RNE
    return (unsigned short)(r >> 16);
}

// ---------------------------------------------------------------------------
// Prep kernels (run every launch; ~80 MB traffic total ≈ 20 us)
// ---------------------------------------------------------------------------
__global__ __launch_bounds__(256) void convert_x(const float* __restrict__ x,
                                                 short* __restrict__ xb) {
    int i = blockIdx.x * 256 + threadIdx.x;          // float4 index
    float4 v = ((const float4*)x)[i];
    short4v o;
    o[0] = (short)f2b(v.x); o[1] = (short)f2b(v.y);
    o[2] = (short)f2b(v.z); o[3] = (short)f2b(v.w);
    ((short4v*)xb)[i] = o;
}

// src [R][C] f32 -> dst [C][R] bf16
__global__ __launch_bounds__(256) void transpose_to_bf16(
    const float* __restrict__ src, short* __restrict__ dst, int R, int C) {
    __shared__ float t[64][65];
    const int c0 = blockIdx.x * 64, r0 = blockIdx.y * 64;
    const int lc = threadIdx.x & 63, lr4 = threadIdx.x >> 6;
    #pragma unroll
    for (int p = 0; p < 16; ++p) {
        int rr = p * 4 + lr4;
        t[rr][lc] = src[(size_t)(r0 + rr) * C + c0 + lc];
    }
    __syncthreads();
    #pragma unroll
    for (int p = 0; p < 16; ++p) {
        int rr = p * 4 + lr4;   // row in dst tile (= source col)
        dst[(size_t)(c0 + rr) * R + r0 + lc] = (short)f2b(t[lc][rr]);
    }
}

// Wq/Wk/Wv [H][1024][64] -> wqkvt [3072][1024] bf16 (n = which*1024 + h*64 + e)
__global__ __launch_bounds__(256) void build_wqkv(
    const float* __restrict__ Wq, const float* __restrict__ Wk,
    const float* __restrict__ Wv, short* __restrict__ dst) {
    const int kt = blockIdx.x, h = blockIdx.y, which = blockIdx.z;
    const float* W = ((which == 0) ? Wq : (which == 1) ? Wk : Wv) +
                     (size_t)h * Dm * HDm;
    __shared__ float t[64][65];
    const int lc = threadIdx.x & 63, lr4 = threadIdx.x >> 6;
    #pragma unroll
    for (int p = 0; p < 16; ++p) {
        int kr = p * 4 + lr4;
        t[kr][lc] = W[(size_t)(kt * 64 + kr) * HDm + lc];
    }
    __syncthreads();
    const int nbase = which * 1024 + h * 64;
    #pragma unroll
    for (int p = 0; p < 16; ++p) {
        int e = p * 4 + lr4;
        dst[(size_t)(nbase + e) * Dm + kt * 64 + lc] = (short)f2b(t[lc][e]);
    }
}

__global__ __launch_bounds__(256) void build_bqkv(
    const float* __restrict__ bq, const float* __restrict__ bk,
    const float* __restrict__ bv, float* __restrict__ bcat) {
    int n = blockIdx.x * 256 + threadIdx.x;
    const float* s = (n < 1024) ? bq : (n < 2048) ? bk : bv;
    bcat[n] = s[n & 1023];
}

// ---------------------------------------------------------------------------
// MFMA GEMM: C[M,N] = A[M,K](bf16) @ Bt[N,K](bf16)^T, 128x128 tile, BK=64.
// 256 thr = 4 waves (2x2); wave owns 64x64 = 4x4 frags of 16x16x32 MFMA.
// global_load_lds width-16 staging; XOR-swizzled LDS (pre-swizzled source).
// EPI 0: outf = acc + bias + res (f32)
// EPI 1: outb = bf16(gelu(acc + bias))
// EPI 2: qkv scatter bf16 [B,H,S,HD], bias = bcat
// ---------------------------------------------------------------------------
template<int EPI>
__global__ __launch_bounds__(256) void gemm_bf16(
    const short* __restrict__ A, const short* __restrict__ Bt,
    const float* __restrict__ bias, const float* __restrict__ res,
    float* __restrict__ outf, short* __restrict__ outb,
    short* __restrict__ qo, short* __restrict__ ko, short* __restrict__ vo,
    int K, int N)
{
    __shared__ __align__(16) char smem[32768];
    char* ldsA = smem;
    char* ldsB = smem + 16384;
    const int tid = threadIdx.x;
    const int l = tid & 63, wv = tid >> 6;
    const int wr = wv >> 1, wc = wv & 1, lr = l & 15, lg = l >> 4;
    const int m0 = blockIdx.x * 128, n0 = blockIdx.y * 128;
    const size_t KB = (size_t)K * 2;
    const char* Ab = (const char*)A;
    const char* Bb = (const char*)Bt;

    f32x4 zero4 = {0.f, 0.f, 0.f, 0.f};
    f32x4 acc[4][4];
    #pragma unroll
    for (int i = 0; i < 4; ++i)
        #pragma unroll
        for (int j = 0; j < 4; ++j) acc[i][j] = zero4;

    const int wbase = wv << 6;   // wave chunk base
    for (int k0 = 0; k0 < K; k0 += 64) {
        __syncthreads();
        #pragma unroll
        for (int r = 0; r < 4; ++r) {
            int c  = wbase + 256 * r;   // wave-uniform LDS chunk base
            int cl = c + l;             // this lane's chunk
            int row = cl >> 3, j = cl & 7;
            int sw = ((j ^ (row & 7)) << 4);
            __builtin_amdgcn_global_load_lds(
                (const __attribute__((address_space(1))) void*)
                    (Ab + (size_t)(m0 + row) * KB + (size_t)k0 * 2 + sw),
                (__attribute__((address_space(3))) void*)(ldsA + c * 16),
                16, 0, 0);
            __builtin_amdgcn_global_load_lds(
                (const __attribute__((address_space(1))) void*)
                    (Bb + (size_t)(n0 + row) * KB + (size_t)k0 * 2 + sw),
                (__attribute__((address_space(3))) void*)(ldsB + c * 16),
                16, 0, 0);
        }
        __syncthreads();
        #pragma unroll
        for (int ks = 0; ks < 2; ++ks) {
            short8 af[4], bf[4];
            #pragma unroll
            for (int i = 0; i < 4; ++i) {
                int rowA = wr * 64 + i * 16 + lr;
                af[i] = *(const short8*)(ldsA + rowA * 128 +
                            (((ks * 4 + lg) ^ (rowA & 7)) << 4));
                int rowB = wc * 64 + i * 16 + lr;
                bf[i] = *(const short8*)(ldsB + rowB * 128 +
                            (((ks * 4 + lg) ^ (rowB & 7)) << 4));
            }
            #pragma unroll
            for (int i = 0; i < 4; ++i)
                #pragma unroll
                for (int jn = 0; jn < 4; ++jn)
                    acc[i][jn] = __builtin_amdgcn_mfma_f32_16x16x32_bf16(
                        af[i], bf[jn], acc[i][jn], 0, 0, 0);
        }
    }

    // epilogue: C frag (i,jn): row m = (lg*4+r), col n = lr
    #pragma unroll
    for (int i = 0; i < 4; ++i) {
        #pragma unroll
        for (int jn = 0; jn < 4; ++jn) {
            #pragma unroll
            for (int r = 0; r < 4; ++r) {
                int m = m0 + wr * 64 + i * 16 + lg * 4 + r;
                int n = n0 + wc * 64 + jn * 16 + lr;
                float val = acc[i][jn][r];
                if (EPI == 0) {
                    val += bias[n] + res[(size_t)m * N + n];
                    outf[(size_t)m * N + n] = val;
                } else if (EPI == 1) {
                    val += bias[n];
                    val = 0.5f * val * (1.0f + erff(val * 0.70710678118654752f));
                    outb[(size_t)m * N + n] = (short)f2b(val);
                } else {
                    val += bias[n];
                    int which = n >> 10, hh = (n >> 6) & 15, e = n & 63;
                    int bb2 = m >> 11, ss = m & 2047;
                    short* o = (which == 0) ? qo : (which == 1) ? ko : vo;
                    o[(((size_t)bb2 * Hh + hh) * Sq + ss) * HDm + e] = (short)f2b(val);
                }
            }
        }
    }
}

// ---------------------------------------------------------------------------
// MFMA flash attention (bf16 in, bf16 ctx out), causal, scale = 1/HD.
// grid (S/64, H, B), 256 thr = 4 waves; wave owns 16 q-rows; KV tiles of 64.
// K tile LDS [64][72] (144B rows -> conflict-free b128); V staged transposed
// [d][key] so PV B-operand reads are contiguous. P via per-wave LDS [16][72].
// ---------------------------------------------------------------------------
__global__ __launch_bounds__(256) void attn_mfma(
    const short* __restrict__ qg, const short* __restrict__ kg,
    const short* __restrict__ vg, short* __restrict__ ctx)
{
    const int qt = blockIdx.x, h = blockIdx.y, b = blockIdx.z;
    const int tid = threadIdx.x;
    const int l = tid & 63, wv = tid >> 4 >> 2;   // wave id
    const int lr = l & 15, lg = l >> 4;
    __shared__ __align__(16) short Kl[64][72];
    __shared__ __align__(16) short Vt[64][72];
    __shared__ __align__(16) short Pl[4][16][72];

    const size_t bh = ((size_t)b * Hh + h) * Sq;
    const float SCALE = 1.0f / 64.0f;

    // Q fragments in registers (A operand: row = lr, k = lg*8 + ks*32 + j)
    const int qrow = qt * 64 + wv * 16 + lr;
    short8 aq[2];
    #pragma unroll
    for (int ks = 0; ks < 2; ++ks)
        aq[ks] = *(const short8*)(qg + (bh + qrow) * HDm + ks * 32 + lg * 8);

    f32x4 zero4 = {0.f, 0.f, 0.f, 0.f};
    f32x4 oacc[4];
    #pragma unroll
    for (int i = 0; i < 4; ++i) oacc[i] = zero4;
    float mreg[4], lreg[4];
    #pragma unroll
    for (int r = 0; r < 4; ++r) { mreg[r] = -3e38f; lreg[r] = 0.f; }

    for (int t = 0; t <= qt; ++t) {
        __syncthreads();   // protect Kl/Vt from previous iteration's readers
        // stage K tile and V^T tile (512 16B chunks each)
        #pragma unroll
        for (int r2 = 0; r2 < 2; ++r2) {
            int c = tid + 256 * r2;
            int krow = c >> 3, kch = c & 7;
            size_t go = (bh + t * 64 + krow) * HDm + kch * 8;
            short8 kv8 = *(const short8*)(kg + go);
            *(short8*)&Kl[krow][kch * 8] = kv8;
            short8 vv8 = *(const short8*)(vg + go);
            #pragma unroll
            for (int j = 0; j < 8; ++j) Vt[kch * 8 + j][krow] = vv8[j];
        }
        __syncthreads();

        // QK^T: S[16 q][64 key]
        f32x4 sc[4];
        #pragma unroll
        for (int i = 0; i < 4; ++i) sc[i] = zero4;
        #pragma unroll
        for (int ks = 0; ks < 2; ++ks) {
            #pragma unroll
            for (int nf = 0; nf < 4; ++nf) {
                short8 bk = *(const short8*)&Kl[nf * 16 + lr][ks * 32 + lg * 8];
                sc[nf] = __builtin_amdgcn_mfma_f32_16x16x32_bf16(
                    aq[ks], bk, sc[nf], 0, 0, 0);
            }
        }

        // scale + causal mask + online softmax (C rows = lg*4 + r)
        #pragma unroll
        for (int r = 0; r < 4; ++r) {
            const int qglob = qt * 64 + wv * 16 + lg * 4 + r;
            float sv[4], mrow = -3e38f;
            #pragma unroll
            for (int nf = 0; nf < 4; ++nf) {
                float s = sc[nf][r] * SCALE;
                if (t * 64 + nf * 16 + lr > qglob) s = -3e38f;
                sv[nf] = s;
                mrow = fmaxf(mrow, s);
            }
            #pragma unroll
            for (int o = 1; o < 16; o <<= 1)
                mrow = fmaxf(mrow, __shfl_xor(mrow, o));
            float mnew = fmaxf(mreg[r], mrow);
            float cf = __expf(mreg[r] - mnew);
            mreg[r] = mnew;
            float ps = 0.f;
            #pragma unroll
            for (int nf = 0; nf < 4; ++nf) {
                float p = __expf(sv[nf] - mnew);
                ps += p;
                Pl[wv][lg * 4 + r][nf * 16 + lr] = (short)f2b(p);
            }
            #pragma unroll
            for (int o = 1; o < 16; o <<= 1)
                ps += __shfl_xor(ps, o);
            lreg[r] = lreg[r] * cf + ps;
            #pragma unroll
            for (int nf = 0; nf < 4; ++nf) oacc[nf][r] *= cf;
        }
        __syncthreads();   // P visible across lanes

        // PV: O[16 q][64 d] += P @ V
        #pragma unroll
        for (int ks = 0; ks < 2; ++ks) {
            short8 pa = *(const short8*)&Pl[wv][lr][ks * 32 + lg * 8];
            #pragma unroll
            for (int nf = 0; nf < 4; ++nf) {
                short8 bv8 = *(const short8*)&Vt[nf * 16 + lr][ks * 32 + lg * 8];
                oacc[nf] = __builtin_amdgcn_mfma_f32_16x16x32_bf16(
                    pa, bv8, oacc[nf], 0, 0, 0);
            }
        }
    }

    // normalize + write ctx [B,S,D] bf16
    #pragma unroll
    for (int r = 0; r < 4; ++r) {
        float inv = 1.0f / lreg[r];
        int qglob = qt * 64 + wv * 16 + lg * 4 + r;
        size_t o = ((size_t)b * Sq + qglob) * Dm + h * HDm;
        #pragma unroll
        for (int nf = 0; nf < 4; ++nf)
            ctx[o + nf * 16 + lr] = (short)f2b(oacc[nf][r] * inv);
    }
}

// ---------------------------------------------------------------------------
// Row LayerNorm: block per row (1024), 256 thr x float4. Optional bf16 copy.
// ---------------------------------------------------------------------------
template<int BF16OUT>
__global__ __launch_bounds__(256) void ln_kernel(
    const float* __restrict__ in, const float* __restrict__ g,
    const float* __restrict__ be, float* __restrict__ outf,
    short* __restrict__ outb)
{
    const int m = blockIdx.x;
    const int tid = threadIdx.x;
    const float4 vl = *(const float4*)&in[(size_t)m * Dm + tid * 4];
    float s  = vl.x + vl.y + vl.z + vl.w;
    float s2 = vl.x * vl.x + vl.y * vl.y + vl.z * vl.z + vl.w * vl.w;
    #pragma unroll
    for (int o = 32; o > 0; o >>= 1) {
        s  += __shfl_down(s, o);
        s2 += __shfl_down(s2, o);
    }
    __shared__ float rs[4], rs2[4];
    const int w = tid >> 6;
    if ((tid & 63) == 0) { rs[w] = s; rs2[w] = s2; }
    __syncthreads();
    s  = rs[0] + rs[1] + rs[2] + rs[3];
    s2 = rs2[0] + rs2[1] + rs2[2] + rs2[3];
    const float mean = s * (1.0f / Dm);
    const float var  = s2 * (1.0f / Dm) - mean * mean;
    const float rstd = rsqrtf(var + 1e-5f);
    const float4 gv = *(const float4*)&g[tid * 4];
    const float4 bv = *(const float4*)&be[tid * 4];
    float4 ov;
    ov.x = (vl.x - mean) * rstd * gv.x + bv.x;
    ov.y = (vl.y - mean) * rstd * gv.y + bv.y;
    ov.z = (vl.z - mean) * rstd * gv.z + bv.z;
    ov.w = (vl.w - mean) * rstd * gv.w + bv.w;
    *(float4*)&outf[(size_t)m * Dm + tid * 4] = ov;
    if (BF16OUT) {
        short4v o4;
        o4[0] = (short)f2b(ov.x); o4[1] = (short)f2b(ov.y);
        o4[2] = (short)f2b(ov.z); o4[3] = (short)f2b(ov.w);
        *(short4v*)&outb[(size_t)m * Dm + tid * 4] = o4;
    }
}

// ---------------------------------------------------------------------------
extern "C" void kernel_launch(void* const* d_in, const int* in_sizes, int n_in,
                              void* d_out, int out_size, void* d_ws, size_t ws_size,
                              hipStream_t stream)
{
    const float* x  = (const float*)d_in[0];
    const float* Wq = (const float*)d_in[1];
    const float* bq = (const float*)d_in[2];
    const float* Wk = (const float*)d_in[3];
    const float* bk = (const float*)d_in[4];
    const float* Wv = (const float*)d_in[5];
    const float* bv = (const float*)d_in[6];
    const float* Wo = (const float*)d_in[7];
    const float* bo = (const float*)d_in[8];
    const float* W1 = (const float*)d_in[9];
    const float* b1 = (const float*)d_in[10];
    const float* W2 = (const float*)d_in[11];
    const float* b2 = (const float*)d_in[12];
    const float* g1 = (const float*)d_in[13];
    const float* be1= (const float*)d_in[14];
    const float* g2 = (const float*)d_in[15];
    const float* be2= (const float*)d_in[16];
    float* out = (float*)d_out;

    char* ws = (char*)d_ws;
    size_t off = 0;
    auto alloc = [&](size_t bytes) {
        char* p = ws + off;
        off += (bytes + 255) & ~(size_t)255;
        return p;
    };
    const size_t MD2 = (size_t)Mm * Dm * 2;          // 8 MB
    short* xb    = (short*)alloc(MD2);
    short* wqkvt = (short*)alloc((size_t)3072 * Dm * 2);
    float* bcat  = (float*)alloc(3072 * 4);
    short* wot   = (short*)alloc((size_t)Dm * Dm * 2);
    short* w1t   = (short*)alloc((size_t)FFm * Dm * 2);
    short* w2t   = (short*)alloc((size_t)Dm * FFm * 2);
    short* qb    = (short*)alloc(MD2);
    short* kb    = (short*)alloc(MD2);
    short* vb    = (short*)alloc(MD2);
    short* ctxb  = (short*)alloc(MD2);
    short* hb    = qb;                                // alias: q/k/v/ctx dead by FF1
    float* y     = (float*)alloc((size_t)Mm * Dm * 4);
    float* x1f   = (float*)alloc((size_t)Mm * Dm * 4);
    short* x1b   = (short*)alloc(MD2);
    float* y2    = y;                                 // alias: y dead after LN1

    // --- weight/activation prep (bf16, transposed) ---
    convert_x<<<Mm * Dm / 1024, 256, 0, stream>>>(x, xb);
    build_wqkv<<<dim3(16, 16, 3), 256, 0, stream>>>(Wq, Wk, Wv, wqkvt);
    build_bqkv<<<12, 256, 0, stream>>>(bq, bk, bv, bcat);
    transpose_to_bf16<<<dim3(16, 16), 256, 0, stream>>>(Wo, wot, Dm, Dm);
    transpose_to_bf16<<<dim3(64, 16), 256, 0, stream>>>(W1, w1t, Dm, FFm);
    transpose_to_bf16<<<dim3(16, 64), 256, 0, stream>>>(W2, w2t, FFm, Dm);

    // --- decoder layer ---
    gemm_bf16<2><<<dim3(32, 24), 256, 0, stream>>>(
        xb, wqkvt, bcat, nullptr, nullptr, nullptr, qb, kb, vb, Dm, 3072);
    attn_mfma<<<dim3(Sq / 64, Hh, Bb), 256, 0, stream>>>(qb, kb, vb, ctxb);
    gemm_bf16<0><<<dim3(32, 8), 256, 0, stream>>>(
        ctxb, wot, bo, x, y, nullptr, nullptr, nullptr, nullptr, Dm, Dm);
    ln_kernel<1><<<Mm, 256, 0, stream>>>(y, g1, be1, x1f, x1b);
    gemm_bf16<1><<<dim3(32, 32), 256, 0, stream>>>(
        x1b, w1t, b1, nullptr, nullptr, hb, nullptr, nullptr, nullptr, Dm, FFm);
    gemm_bf16<0><<<dim3(32, 8), 256, 0, stream>>>(
        hb, w2t, b2, x1f, y2, nullptr, nullptr, nullptr, nullptr, FFm, Dm);
    ln_kernel<0><<<Mm, 256, 0, stream>>>(y2, g2, be2, out, nullptr);
}

// Round 3
// 324.608 us; speedup vs baseline: 7.4896x; 1.2506x over previous
//
#include <hip/hip_runtime.h>
#include <math.h>

// Problem constants
constexpr int Dm  = 1024;
constexpr int Hh  = 16;
constexpr int HDm = 64;
constexpr int FFm = 4096;
constexpr int Bb  = 2;
constexpr int Sq  = 2048;
constexpr int Mm  = Bb * Sq;   // 4096 rows

typedef __attribute__((ext_vector_type(8))) short short8;
typedef __attribute__((ext_vector_type(4))) short short4v;
typedef __attribute__((ext_vector_type(4))) float f32x4;

__device__ __forceinline__ unsigned short f2b(float f) {
    union { float f; unsigned u; } v; v.f = f;
    unsigned r = v.u + 0x7FFFu + ((v.u >> 16) & 1u);   // RNE
    return (unsigned short)(r >> 16);
}

// ---------------------------------------------------------------------------
// Prep kernels
// ---------------------------------------------------------------------------
__global__ __launch_bounds__(256) void convert_x(const float* __restrict__ x,
                                                 short* __restrict__ xb) {
    int i = blockIdx.x * 256 + threadIdx.x;          // float4 index
    float4 v = ((const float4*)x)[i];
    short4v o;
    o[0] = (short)f2b(v.x); o[1] = (short)f2b(v.y);
    o[2] = (short)f2b(v.z); o[3] = (short)f2b(v.w);
    ((short4v*)xb)[i] = o;
}

// src [R][C] f32 -> dst [C][R] bf16
__global__ __launch_bounds__(256) void transpose_to_bf16(
    const float* __restrict__ src, short* __restrict__ dst, int R, int C) {
    __shared__ float t[64][65];
    const int c0 = blockIdx.x * 64, r0 = blockIdx.y * 64;
    const int lc = threadIdx.x & 63, lr4 = threadIdx.x >> 6;
    #pragma unroll
    for (int p = 0; p < 16; ++p) {
        int rr = p * 4 + lr4;
        t[rr][lc] = src[(size_t)(r0 + rr) * C + c0 + lc];
    }
    __syncthreads();
    #pragma unroll
    for (int p = 0; p < 16; ++p) {
        int rr = p * 4 + lr4;   // row in dst tile (= source col)
        dst[(size_t)(c0 + rr) * R + r0 + lc] = (short)f2b(t[lc][rr]);
    }
}

// Wq/Wk/Wv [H][1024][64] -> wqkvt [3072][1024] bf16 (n = which*1024 + h*64 + e)
__global__ __launch_bounds__(256) void build_wqkv(
    const float* __restrict__ Wq, const float* __restrict__ Wk,
    const float* __restrict__ Wv, short* __restrict__ dst) {
    const int kt = blockIdx.x, h = blockIdx.y, which = blockIdx.z;
    const float* W = ((which == 0) ? Wq : (which == 1) ? Wk : Wv) +
                     (size_t)h * Dm * HDm;
    __shared__ float t[64][65];
    const int lc = threadIdx.x & 63, lr4 = threadIdx.x >> 6;
    #pragma unroll
    for (int p = 0; p < 16; ++p) {
        int kr = p * 4 + lr4;
        t[kr][lc] = W[(size_t)(kt * 64 + kr) * HDm + lc];
    }
    __syncthreads();
    const int nbase = which * 1024 + h * 64;
    #pragma unroll
    for (int p = 0; p < 16; ++p) {
        int e = p * 4 + lr4;
        dst[(size_t)(nbase + e) * Dm + kt * 64 + lc] = (short)f2b(t[lc][e]);
    }
}

__global__ __launch_bounds__(256) void build_bqkv(
    const float* __restrict__ bq, const float* __restrict__ bk,
    const float* __restrict__ bv, float* __restrict__ bcat) {
    int n = blockIdx.x * 256 + threadIdx.x;
    const float* s = (n < 1024) ? bq : (n < 2048) ? bk : bv;
    bcat[n] = s[n & 1023];
}

// V [B,H,S,64] bf16 -> Vt [B,H,64,S] bf16
__global__ __launch_bounds__(256) void transpose_v(
    const short* __restrict__ v, short* __restrict__ vt)
{
    const int st = blockIdx.x;                 // S tile of 64
    const int h = blockIdx.y & 15, b = blockIdx.y >> 4;
    __shared__ short t[64][72];
    const int tid = threadIdx.x;
    const size_t base = ((size_t)b * Hh + h) * Sq * HDm;
    #pragma unroll
    for (int r = 0; r < 2; ++r) {
        int c = tid + 256 * r;
        int srow = c >> 3, sch = c & 7;
        *(short8*)&t[srow][sch * 8] =
            *(const short8*)(v + base + (size_t)(st * 64 + srow) * HDm + sch * 8);
    }
    __syncthreads();
    const size_t obase = ((size_t)b * Hh + h) * HDm * Sq;
    #pragma unroll
    for (int r = 0; r < 2; ++r) {
        int c = tid + 256 * r;
        int erow = c >> 3, sch = c & 7;
        short8 o8;
        #pragma unroll
        for (int j = 0; j < 8; ++j) o8[j] = t[sch * 8 + j][erow];
        *(short8*)(vt + obase + (size_t)erow * Sq + st * 64 + sch * 8) = o8;
    }
}

// ---------------------------------------------------------------------------
// MFMA GEMM: C[M,N] = A[M,K](bf16) @ Bt[N,K](bf16)^T, 128x128 tile, BK=64.
// ---------------------------------------------------------------------------
template<int EPI>
__global__ __launch_bounds__(256) void gemm_bf16(
    const short* __restrict__ A, const short* __restrict__ Bt,
    const float* __restrict__ bias, const float* __restrict__ res,
    float* __restrict__ outf, short* __restrict__ outb,
    short* __restrict__ qo, short* __restrict__ ko, short* __restrict__ vo,
    int K, int N)
{
    __shared__ __align__(16) char smem[32768];
    char* ldsA = smem;
    char* ldsB = smem + 16384;
    const int tid = threadIdx.x;
    const int l = tid & 63, wv = tid >> 6;
    const int wr = wv >> 1, wc = wv & 1, lr = l & 15, lg = l >> 4;
    const int m0 = blockIdx.x * 128, n0 = blockIdx.y * 128;
    const size_t KB = (size_t)K * 2;
    const char* Ab = (const char*)A;
    const char* Bb = (const char*)Bt;

    f32x4 zero4 = {0.f, 0.f, 0.f, 0.f};
    f32x4 acc[4][4];
    #pragma unroll
    for (int i = 0; i < 4; ++i)
        #pragma unroll
        for (int j = 0; j < 4; ++j) acc[i][j] = zero4;

    const int wbase = wv << 6;   // wave chunk base
    for (int k0 = 0; k0 < K; k0 += 64) {
        __syncthreads();
        #pragma unroll
        for (int r = 0; r < 4; ++r) {
            int c  = wbase + 256 * r;   // wave-uniform LDS chunk base
            int cl = c + l;             // this lane's chunk
            int row = cl >> 3, j = cl & 7;
            int sw = ((j ^ (row & 7)) << 4);
            __builtin_amdgcn_global_load_lds(
                (const __attribute__((address_space(1))) void*)
                    (Ab + (size_t)(m0 + row) * KB + (size_t)k0 * 2 + sw),
                (__attribute__((address_space(3))) void*)(ldsA + c * 16),
                16, 0, 0);
            __builtin_amdgcn_global_load_lds(
                (const __attribute__((address_space(1))) void*)
                    (Bb + (size_t)(n0 + row) * KB + (size_t)k0 * 2 + sw),
                (__attribute__((address_space(3))) void*)(ldsB + c * 16),
                16, 0, 0);
        }
        __syncthreads();
        #pragma unroll
        for (int ks = 0; ks < 2; ++ks) {
            short8 af[4], bf[4];
            #pragma unroll
            for (int i = 0; i < 4; ++i) {
                int rowA = wr * 64 + i * 16 + lr;
                af[i] = *(const short8*)(ldsA + rowA * 128 +
                            (((ks * 4 + lg) ^ (rowA & 7)) << 4));
                int rowB = wc * 64 + i * 16 + lr;
                bf[i] = *(const short8*)(ldsB + rowB * 128 +
                            (((ks * 4 + lg) ^ (rowB & 7)) << 4));
            }
            #pragma unroll
            for (int i = 0; i < 4; ++i)
                #pragma unroll
                for (int jn = 0; jn < 4; ++jn)
                    acc[i][jn] = __builtin_amdgcn_mfma_f32_16x16x32_bf16(
                        af[i], bf[jn], acc[i][jn], 0, 0, 0);
        }
    }

    // epilogue: C frag (i,jn): row m = (lg*4+r), col n = lr
    #pragma unroll
    for (int i = 0; i < 4; ++i) {
        #pragma unroll
        for (int jn = 0; jn < 4; ++jn) {
            #pragma unroll
            for (int r = 0; r < 4; ++r) {
                int m = m0 + wr * 64 + i * 16 + lg * 4 + r;
                int n = n0 + wc * 64 + jn * 16 + lr;
                float val = acc[i][jn][r];
                if (EPI == 0) {
                    val += bias[n] + res[(size_t)m * N + n];
                    outf[(size_t)m * N + n] = val;
                } else if (EPI == 1) {
                    val += bias[n];
                    val = 0.5f * val * (1.0f + erff(val * 0.70710678118654752f));
                    outb[(size_t)m * N + n] = (short)f2b(val);
                } else {
                    val += bias[n];
                    int which = n >> 10, hh = (n >> 6) & 15, e = n & 63;
                    int bb2 = m >> 11, ss = m & 2047;
                    short* o = (which == 0) ? qo : (which == 1) ? ko : vo;
                    o[(((size_t)bb2 * Hh + hh) * Sq + ss) * HDm + e] = (short)f2b(val);
                }
            }
        }
    }
}

// ---------------------------------------------------------------------------
// MFMA flash attention v2.
// Grid: 512 blocks (flat), heavy-first qt order. Block = 512 thr = 8 waves.
// Q-block = 128 rows; wave owns 16 q-rows. KV tile = 64.
// K staged [64 key][72] (pad -> 2-way max on b128 = free).
// V read from pre-transposed Vt [B,H,64,S]; staged [64 d][72 key].
// P per-wave in LDS; no block barrier between softmax and PV (wave-local,
// ordered by inline lgkmcnt(0) + sched_barrier per guide rule #18).
// ---------------------------------------------------------------------------
__global__ __launch_bounds__(512) void attn_mfma(
    const short* __restrict__ qg, const short* __restrict__ kg,
    const short* __restrict__ vtg, short* __restrict__ ctx)
{
    const int bid = blockIdx.x;
    const int qt = (Sq / 128 - 1) - (bid >> 5);    // heavy blocks first
    const int hb = bid & 31;
    const int h = hb & 15, b = hb >> 4;
    const int tid = threadIdx.x;
    const int l = tid & 63, wv = tid >> 6;
    const int lr = l & 15, lg = l >> 4;

    __shared__ __align__(16) short Kl[64][72];
    __shared__ __align__(16) short Vtl[64][72];
    __shared__ __align__(16) short Pl[8][16][72];

    const size_t bh = ((size_t)b * Hh + h) * Sq;
    const size_t vbase = ((size_t)b * Hh + h) * HDm * Sq;
    const float SCALE = 1.0f / 64.0f;

    const int qbase = qt * 128 + wv * 16;
    short8 aq[2];
    #pragma unroll
    for (int ks = 0; ks < 2; ++ks)
        aq[ks] = *(const short8*)(qg + (bh + qbase + lr) * HDm + ks * 32 + lg * 8);

    f32x4 zero4 = {0.f, 0.f, 0.f, 0.f};
    f32x4 oacc[4];
    #pragma unroll
    for (int i = 0; i < 4; ++i) oacc[i] = zero4;
    float mreg[4], lreg[4];
    #pragma unroll
    for (int r = 0; r < 4; ++r) { mreg[r] = -3e38f; lreg[r] = 0.f; }

    const int nt = 2 * qt + 2;
    for (int t = 0; t < nt; ++t) {
        __syncthreads();   // protect Kl/Vtl from previous iteration's readers
        {
            int krow = tid >> 3, kch = tid & 7;
            *(short8*)&Kl[krow][kch * 8] =
                *(const short8*)(kg + (bh + t * 64 + krow) * HDm + kch * 8);
            *(short8*)&Vtl[krow][kch * 8] =
                *(const short8*)(vtg + vbase + (size_t)krow * Sq + t * 64 + kch * 8);
        }
        __syncthreads();

        if (t * 64 > qbase + 15) continue;   // tile fully masked for this wave

        // QK^T: S[16 q][64 key]
        f32x4 sc[4];
        #pragma unroll
        for (int i = 0; i < 4; ++i) sc[i] = zero4;
        #pragma unroll
        for (int ks = 0; ks < 2; ++ks) {
            #pragma unroll
            for (int nf = 0; nf < 4; ++nf) {
                short8 bk = *(const short8*)&Kl[nf * 16 + lr][ks * 32 + lg * 8];
                sc[nf] = __builtin_amdgcn_mfma_f32_16x16x32_bf16(
                    aq[ks], bk, sc[nf], 0, 0, 0);
            }
        }

        const bool needmask = (t * 64 + 63 > qbase);
        #pragma unroll
        for (int r = 0; r < 4; ++r) {
            const int qglob = qbase + lg * 4 + r;
            float sv[4], mrow = -3e38f;
            #pragma unroll
            for (int nf = 0; nf < 4; ++nf) {
                float s = sc[nf][r] * SCALE;
                if (needmask && (t * 64 + nf * 16 + lr > qglob)) s = -3e38f;
                sv[nf] = s;
                mrow = fmaxf(mrow, s);
            }
            #pragma unroll
            for (int o = 1; o < 16; o <<= 1)
                mrow = fmaxf(mrow, __shfl_xor(mrow, o));
            float mnew = fmaxf(mreg[r], mrow);
            float cf = __expf(mreg[r] - mnew);
            mreg[r] = mnew;
            float ps = 0.f;
            #pragma unroll
            for (int nf = 0; nf < 4; ++nf) {
                float p = __expf(sv[nf] - mnew);
                ps += p;
                Pl[wv][lg * 4 + r][nf * 16 + lr] = (short)f2b(p);
            }
            #pragma unroll
            for (int o = 1; o < 16; o <<= 1)
                ps += __shfl_xor(ps, o);
            lreg[r] = lreg[r] * cf + ps;
            #pragma unroll
            for (int nf = 0; nf < 4; ++nf) oacc[nf][r] *= cf;
        }

        // P is wave-local: order LDS writes before reads without block barrier
        asm volatile("s_waitcnt lgkmcnt(0)" ::: "memory");
        __builtin_amdgcn_sched_barrier(0);

        // PV: O[16 q][64 d] += P @ V
        #pragma unroll
        for (int ks = 0; ks < 2; ++ks) {
            short8 pa = *(const short8*)&Pl[wv][lr][ks * 32 + lg * 8];
            #pragma unroll
            for (int nf = 0; nf < 4; ++nf) {
                short8 bv8 = *(const short8*)&Vtl[nf * 16 + lr][ks * 32 + lg * 8];
                oacc[nf] = __builtin_amdgcn_mfma_f32_16x16x32_bf16(
                    pa, bv8, oacc[nf], 0, 0, 0);
            }
        }
    }

    // normalize + write ctx [B,S,D] bf16
    #pragma unroll
    for (int r = 0; r < 4; ++r) {
        float inv = 1.0f / lreg[r];
        int q = qbase + lg * 4 + r;
        size_t o = ((size_t)b * Sq + q) * Dm + h * HDm;
        #pragma unroll
        for (int nf = 0; nf < 4; ++nf)
            ctx[o + nf * 16 + lr] = (short)f2b(oacc[nf][r] * inv);
    }
}

// ---------------------------------------------------------------------------
// Row LayerNorm: block per row (1024), 256 thr x float4. Optional bf16 copy.
// ---------------------------------------------------------------------------
template<int BF16OUT>
__global__ __launch_bounds__(256) void ln_kernel(
    const float* __restrict__ in, const float* __restrict__ g,
    const float* __restrict__ be, float* __restrict__ outf,
    short* __restrict__ outb)
{
    const int m = blockIdx.x;
    const int tid = threadIdx.x;
    const float4 vl = *(const float4*)&in[(size_t)m * Dm + tid * 4];
    float s  = vl.x + vl.y + vl.z + vl.w;
    float s2 = vl.x * vl.x + vl.y * vl.y + vl.z * vl.z + vl.w * vl.w;
    #pragma unroll
    for (int o = 32; o > 0; o >>= 1) {
        s  += __shfl_down(s, o);
        s2 += __shfl_down(s2, o);
    }
    __shared__ float rs[4], rs2[4];
    const int w = tid >> 6;
    if ((tid & 63) == 0) { rs[w] = s; rs2[w] = s2; }
    __syncthreads();
    s  = rs[0] + rs[1] + rs[2] + rs[3];
    s2 = rs2[0] + rs2[1] + rs2[2] + rs2[3];
    const float mean = s * (1.0f / Dm);
    const float var  = s2 * (1.0f / Dm) - mean * mean;
    const float rstd = rsqrtf(var + 1e-5f);
    const float4 gv = *(const float4*)&g[tid * 4];
    const float4 bv = *(const float4*)&be[tid * 4];
    float4 ov;
    ov.x = (vl.x - mean) * rstd * gv.x + bv.x;
    ov.y = (vl.y - mean) * rstd * gv.y + bv.y;
    ov.z = (vl.z - mean) * rstd * gv.z + bv.z;
    ov.w = (vl.w - mean) * rstd * gv.w + bv.w;
    *(float4*)&outf[(size_t)m * Dm + tid * 4] = ov;
    if (BF16OUT) {
        short4v o4;
        o4[0] = (short)f2b(ov.x); o4[1] = (short)f2b(ov.y);
        o4[2] = (short)f2b(ov.z); o4[3] = (short)f2b(ov.w);
        *(short4v*)&outb[(size_t)m * Dm + tid * 4] = o4;
    }
}

// ---------------------------------------------------------------------------
extern "C" void kernel_launch(void* const* d_in, const int* in_sizes, int n_in,
                              void* d_out, int out_size, void* d_ws, size_t ws_size,
                              hipStream_t stream)
{
    const float* x  = (const float*)d_in[0];
    const float* Wq = (const float*)d_in[1];
    const float* bq = (const float*)d_in[2];
    const float* Wk = (const float*)d_in[3];
    const float* bk = (const float*)d_in[4];
    const float* Wv = (const float*)d_in[5];
    const float* bv = (const float*)d_in[6];
    const float* Wo = (const float*)d_in[7];
    const float* bo = (const float*)d_in[8];
    const float* W1 = (const float*)d_in[9];
    const float* b1 = (const float*)d_in[10];
    const float* W2 = (const float*)d_in[11];
    const float* b2 = (const float*)d_in[12];
    const float* g1 = (const float*)d_in[13];
    const float* be1= (const float*)d_in[14];
    const float* g2 = (const float*)d_in[15];
    const float* be2= (const float*)d_in[16];
    float* out = (float*)d_out;

    char* ws = (char*)d_ws;
    size_t off = 0;
    auto alloc = [&](size_t bytes) {
        char* p = ws + off;
        off += (bytes + 255) & ~(size_t)255;
        return p;
    };
    const size_t MD2 = (size_t)Mm * Dm * 2;          // 8 MB
    short* xb    = (short*)alloc(MD2);
    short* wqkvt = (short*)alloc((size_t)3072 * Dm * 2);
    float* bcat  = (float*)alloc(3072 * 4);
    short* wot   = (short*)alloc((size_t)Dm * Dm * 2);
    short* w1t   = (short*)alloc((size_t)FFm * Dm * 2);
    short* w2t   = (short*)alloc((size_t)Dm * FFm * 2);
    short* qb    = (short*)alloc(MD2);
    short* kb    = (short*)alloc(MD2);
    short* vb    = (short*)alloc(MD2);
    short* ctxb  = (short*)alloc(MD2);
    short* hb    = qb;                                // alias: q/k/v/ctx dead by FF1
    float* y     = (float*)alloc((size_t)Mm * Dm * 4);
    float* x1f   = (float*)alloc((size_t)Mm * Dm * 4);
    short* x1b   = (short*)alloc(MD2);
    float* y2    = y;                                 // alias: y dead after LN1
    short* vtb   = (short*)y;                         // alias: vtb dead before Wo-gemm writes y

    // --- weight/activation prep (bf16, transposed) ---
    convert_x<<<Mm * Dm / 1024, 256, 0, stream>>>(x, xb);
    build_wqkv<<<dim3(16, 16, 3), 256, 0, stream>>>(Wq, Wk, Wv, wqkvt);
    build_bqkv<<<12, 256, 0, stream>>>(bq, bk, bv, bcat);
    transpose_to_bf16<<<dim3(16, 16), 256, 0, stream>>>(Wo, wot, Dm, Dm);
    transpose_to_bf16<<<dim3(64, 16), 256, 0, stream>>>(W1, w1t, Dm, FFm);
    transpose_to_bf16<<<dim3(16, 64), 256, 0, stream>>>(W2, w2t, FFm, Dm);

    // --- decoder layer ---
    gemm_bf16<2><<<dim3(32, 24), 256, 0, stream>>>(
        xb, wqkvt, bcat, nullptr, nullptr, nullptr, qb, kb, vb, Dm, 3072);
    transpose_v<<<dim3(32, 32), 256, 0, stream>>>(vb, vtb);
    attn_mfma<<<512, 512, 0, stream>>>(qb, kb, vtb, ctxb);
    gemm_bf16<0><<<dim3(32, 8), 256, 0, stream>>>(
        ctxb, wot, bo, x, y, nullptr, nullptr, nullptr, nullptr, Dm, Dm);
    ln_kernel<1><<<Mm, 256, 0, stream>>>(y, g1, be1, x1f, x1b);
    gemm_bf16<1><<<dim3(32, 32), 256, 0, stream>>>(
        x1b, w1t, b1, nullptr, nullptr, hb, nullptr, nullptr, nullptr, Dm, FFm);
    gemm_bf16<0><<<dim3(32, 8), 256, 0, stream>>>(
        hb, w2t, b2, x1f, y2, nullptr, nullptr, nullptr, nullptr, FFm, Dm);
    ln_kernel<0><<<Mm, 256, 0, stream>>>(y2, g2, be2, out, nullptr);
}

// Round 4
// 292.236 us; speedup vs baseline: 8.3193x; 1.1108x over previous
//
#include <hip/hip_runtime.h>
#include <math.h>

// Problem constants
constexpr int Dm  = 1024;
constexpr int Hh  = 16;
constexpr int HDm = 64;
constexpr int FFm = 4096;
constexpr int Bb  = 2;
constexpr int Sq  = 2048;
constexpr int Mm  = Bb * Sq;   // 4096 rows

typedef __attribute__((ext_vector_type(8))) short short8;
typedef __attribute__((ext_vector_type(4))) short short4v;
typedef __attribute__((ext_vector_type(4))) float f32x4;

__device__ __forceinline__ unsigned short f2b(float f) {
    union { float f; unsigned u; } v; v.f = f;
    unsigned r = v.u + 0x7FFFu + ((v.u >> 16) & 1u);   // RNE
    return (unsigned short)(r >> 16);
}

// ---------------------------------------------------------------------------
// Prep kernels
// ---------------------------------------------------------------------------
__global__ __launch_bounds__(256) void convert_x(const float* __restrict__ x,
                                                 short* __restrict__ xb) {
    int i = blockIdx.x * 256 + threadIdx.x;          // float4 index
    float4 v = ((const float4*)x)[i];
    short4v o;
    o[0] = (short)f2b(v.x); o[1] = (short)f2b(v.y);
    o[2] = (short)f2b(v.z); o[3] = (short)f2b(v.w);
    ((short4v*)xb)[i] = o;
}

// src [R][C] f32 -> dst [C][R] bf16
__global__ __launch_bounds__(256) void transpose_to_bf16(
    const float* __restrict__ src, short* __restrict__ dst, int R, int C) {
    __shared__ float t[64][65];
    const int c0 = blockIdx.x * 64, r0 = blockIdx.y * 64;
    const int lc = threadIdx.x & 63, lr4 = threadIdx.x >> 6;
    #pragma unroll
    for (int p = 0; p < 16; ++p) {
        int rr = p * 4 + lr4;
        t[rr][lc] = src[(size_t)(r0 + rr) * C + c0 + lc];
    }
    __syncthreads();
    #pragma unroll
    for (int p = 0; p < 16; ++p) {
        int rr = p * 4 + lr4;   // row in dst tile (= source col)
        dst[(size_t)(c0 + rr) * R + r0 + lc] = (short)f2b(t[lc][rr]);
    }
}

// Wq/Wk/Wv [H][1024][64] -> wqkvt [3072][1024] bf16 (n = which*1024 + h*64 + e)
__global__ __launch_bounds__(256) void build_wqkv(
    const float* __restrict__ Wq, const float* __restrict__ Wk,
    const float* __restrict__ Wv, short* __restrict__ dst) {
    const int kt = blockIdx.x, h = blockIdx.y, which = blockIdx.z;
    const float* W = ((which == 0) ? Wq : (which == 1) ? Wk : Wv) +
                     (size_t)h * Dm * HDm;
    __shared__ float t[64][65];
    const int lc = threadIdx.x & 63, lr4 = threadIdx.x >> 6;
    #pragma unroll
    for (int p = 0; p < 16; ++p) {
        int kr = p * 4 + lr4;
        t[kr][lc] = W[(size_t)(kt * 64 + kr) * HDm + lc];
    }
    __syncthreads();
    const int nbase = which * 1024 + h * 64;
    #pragma unroll
    for (int p = 0; p < 16; ++p) {
        int e = p * 4 + lr4;
        dst[(size_t)(nbase + e) * Dm + kt * 64 + lc] = (short)f2b(t[lc][e]);
    }
}

__global__ __launch_bounds__(256) void build_bqkv(
    const float* __restrict__ bq, const float* __restrict__ bk,
    const float* __restrict__ bv, float* __restrict__ bcat) {
    int n = blockIdx.x * 256 + threadIdx.x;
    const float* s = (n < 1024) ? bq : (n < 2048) ? bk : bv;
    bcat[n] = s[n & 1023];
}

// V [B,H,S,64] bf16 -> Vt [B,H,64,S] bf16
__global__ __launch_bounds__(256) void transpose_v(
    const short* __restrict__ v, short* __restrict__ vt)
{
    const int st = blockIdx.x;                 // S tile of 64
    const int h = blockIdx.y & 15, b = blockIdx.y >> 4;
    __shared__ short t[64][72];
    const int tid = threadIdx.x;
    const size_t base = ((size_t)b * Hh + h) * Sq * HDm;
    #pragma unroll
    for (int r = 0; r < 2; ++r) {
        int c = tid + 256 * r;
        int srow = c >> 3, sch = c & 7;
        *(short8*)&t[srow][sch * 8] =
            *(const short8*)(v + base + (size_t)(st * 64 + srow) * HDm + sch * 8);
    }
    __syncthreads();
    const size_t obase = ((size_t)b * Hh + h) * HDm * Sq;
    #pragma unroll
    for (int r = 0; r < 2; ++r) {
        int c = tid + 256 * r;
        int erow = c >> 3, sch = c & 7;
        short8 o8;
        #pragma unroll
        for (int j = 0; j < 8; ++j) o8[j] = t[sch * 8 + j][erow];
        *(short8*)(vt + obase + (size_t)erow * Sq + st * 64 + sch * 8) = o8;
    }
}

// ---------------------------------------------------------------------------
// MFMA GEMM: C[M,N] = A[M,K](bf16) @ Bt[N,K](bf16)^T, BMx128 tile, BK=64.
// BM=128: 4 waves 2x2, wave 64x64. BM=64: 4 waves 2x2, wave 32x64
// (used when grid would otherwise be 1 block/CU).
// ---------------------------------------------------------------------------
template<int EPI, int BM>
__global__ __launch_bounds__(256) void gemm_bf16(
    const short* __restrict__ A, const short* __restrict__ Bt,
    const float* __restrict__ bias, const float* __restrict__ res,
    float* __restrict__ outf, short* __restrict__ outb,
    short* __restrict__ qo, short* __restrict__ ko, short* __restrict__ vo,
    int K, int N)
{
    constexpr int BMW = BM / 2;       // wave M extent
    constexpr int MF  = BMW / 16;     // M fragments per wave
    __shared__ __align__(16) char smem[BM * 128 + 16384];
    char* ldsA = smem;
    char* ldsB = smem + BM * 128;
    const int tid = threadIdx.x;
    const int l = tid & 63, wv = tid >> 6;
    const int wr = wv >> 1, wc = wv & 1, lr = l & 15, lg = l >> 4;
    const int m0 = blockIdx.x * BM, n0 = blockIdx.y * 128;
    const size_t KB = (size_t)K * 2;
    const char* Ab = (const char*)A;
    const char* Bb = (const char*)Bt;

    f32x4 zero4 = {0.f, 0.f, 0.f, 0.f};
    f32x4 acc[MF][4];
    #pragma unroll
    for (int i = 0; i < MF; ++i)
        #pragma unroll
        for (int j = 0; j < 4; ++j) acc[i][j] = zero4;

    for (int k0 = 0; k0 < K; k0 += 64) {
        __syncthreads();
        #pragma unroll
        for (int r = 0; r < BM / 32; ++r) {          // A: BM*8 chunks
            int c  = (wv * (BM / 32) + r) * 64;
            int cl = c + l;
            int row = cl >> 3, j = cl & 7;
            int sw = ((j ^ (row & 7)) << 4);
            __builtin_amdgcn_global_load_lds(
                (const __attribute__((address_space(1))) void*)
                    (Ab + (size_t)(m0 + row) * KB + (size_t)k0 * 2 + sw),
                (__attribute__((address_space(3))) void*)(ldsA + c * 16),
                16, 0, 0);
        }
        #pragma unroll
        for (int r = 0; r < 4; ++r) {                // B: 1024 chunks
            int c  = (wv * 4 + r) * 64;
            int cl = c + l;
            int row = cl >> 3, j = cl & 7;
            int sw = ((j ^ (row & 7)) << 4);
            __builtin_amdgcn_global_load_lds(
                (const __attribute__((address_space(1))) void*)
                    (Bb + (size_t)(n0 + row) * KB + (size_t)k0 * 2 + sw),
                (__attribute__((address_space(3))) void*)(ldsB + c * 16),
                16, 0, 0);
        }
        __syncthreads();
        #pragma unroll
        for (int ks = 0; ks < 2; ++ks) {
            short8 af[MF], bf[4];
            #pragma unroll
            for (int i = 0; i < MF; ++i) {
                int rowA = wr * BMW + i * 16 + lr;
                af[i] = *(const short8*)(ldsA + rowA * 128 +
                            (((ks * 4 + lg) ^ (rowA & 7)) << 4));
            }
            #pragma unroll
            for (int i = 0; i < 4; ++i) {
                int rowB = wc * 64 + i * 16 + lr;
                bf[i] = *(const short8*)(ldsB + rowB * 128 +
                            (((ks * 4 + lg) ^ (rowB & 7)) << 4));
            }
            #pragma unroll
            for (int i = 0; i < MF; ++i)
                #pragma unroll
                for (int jn = 0; jn < 4; ++jn)
                    acc[i][jn] = __builtin_amdgcn_mfma_f32_16x16x32_bf16(
                        af[i], bf[jn], acc[i][jn], 0, 0, 0);
        }
    }

    // epilogue: C frag (i,jn): row m = (lg*4+r), col n = lr
    #pragma unroll
    for (int i = 0; i < MF; ++i) {
        #pragma unroll
        for (int jn = 0; jn < 4; ++jn) {
            #pragma unroll
            for (int r = 0; r < 4; ++r) {
                int m = m0 + wr * BMW + i * 16 + lg * 4 + r;
                int n = n0 + wc * 64 + jn * 16 + lr;
                float val = acc[i][jn][r];
                if (EPI == 0) {
                    val += bias[n] + res[(size_t)m * N + n];
                    outf[(size_t)m * N + n] = val;
                } else if (EPI == 1) {
                    val += bias[n];
                    val = 0.5f * val * (1.0f + erff(val * 0.70710678118654752f));
                    outb[(size_t)m * N + n] = (short)f2b(val);
                } else {
                    val += bias[n];
                    int which = n >> 10, hh = (n >> 6) & 15, e = n & 63;
                    int bb2 = m >> 11, ss = m & 2047;
                    short* o = (which == 0) ? qo : (which == 1) ? ko : vo;
                    o[(((size_t)bb2 * Hh + hh) * Sq + ss) * HDm + e] = (short)f2b(val);
                }
            }
        }
    }
}

// ---------------------------------------------------------------------------
// MFMA flash attention v3.
// Grid: 1024 flat blocks (heavy-first qt), block = 256 thr = 4 waves.
// Q-block = 64 rows; wave owns 16 q-rows. KV tile = 64.
// exp2-domain online softmax (v_exp_f32 native) + defer-max (THR=8 log2).
// K staged [64][72]; V pre-transposed global, staged [64 d][72 key].
// ---------------------------------------------------------------------------
__global__ __launch_bounds__(256) void attn_mfma(
    const short* __restrict__ qg, const short* __restrict__ kg,
    const short* __restrict__ vtg, short* __restrict__ ctx)
{
    const int bid = blockIdx.x;
    const int qt = (Sq / 64 - 1) - (bid >> 5);    // heavy blocks first
    const int hb = bid & 31;
    const int h = hb & 15, b = hb >> 4;
    const int tid = threadIdx.x;
    const int l = tid & 63, wv = tid >> 6;
    const int lr = l & 15, lg = l >> 4;

    __shared__ __align__(16) short Kl[64][72];
    __shared__ __align__(16) short Vtl[64][72];
    __shared__ __align__(16) short Pl[4][16][72];

    const size_t bh = ((size_t)b * Hh + h) * Sq;
    const size_t vbase = ((size_t)b * Hh + h) * HDm * Sq;
    // scores * (1/64) in exp2 domain: fold log2(e)/64 into the scale
    const float SCALE2 = 1.4426950408889634f / 64.0f;
    const float THR = 8.0f;   // defer-max threshold (log2 units; p <= 256)

    const int qbase = qt * 64 + wv * 16;
    short8 aq[2];
    #pragma unroll
    for (int ks = 0; ks < 2; ++ks)
        aq[ks] = *(const short8*)(qg + (bh + qbase + lr) * HDm + ks * 32 + lg * 8);

    f32x4 zero4 = {0.f, 0.f, 0.f, 0.f};
    f32x4 oacc[4];
    #pragma unroll
    for (int i = 0; i < 4; ++i) oacc[i] = zero4;
    float mreg[4], lreg[4];
    #pragma unroll
    for (int r = 0; r < 4; ++r) { mreg[r] = -3e38f; lreg[r] = 0.f; }

    const int nt = qt + 1;
    for (int t = 0; t < nt; ++t) {
        __syncthreads();   // protect Kl/Vtl from previous iteration's readers
        #pragma unroll
        for (int r2 = 0; r2 < 2; ++r2) {
            int c = tid + 256 * r2;
            int krow = c >> 3, kch = c & 7;
            *(short8*)&Kl[krow][kch * 8] =
                *(const short8*)(kg + (bh + t * 64 + krow) * HDm + kch * 8);
            *(short8*)&Vtl[krow][kch * 8] =
                *(const short8*)(vtg + vbase + (size_t)krow * Sq + t * 64 + kch * 8);
        }
        __syncthreads();

        // QK^T: S[16 q][64 key]
        f32x4 sc[4];
        #pragma unroll
        for (int i = 0; i < 4; ++i) sc[i] = zero4;
        __builtin_amdgcn_s_setprio(1);
        #pragma unroll
        for (int ks = 0; ks < 2; ++ks) {
            #pragma unroll
            for (int nf = 0; nf < 4; ++nf) {
                short8 bk = *(const short8*)&Kl[nf * 16 + lr][ks * 32 + lg * 8];
                sc[nf] = __builtin_amdgcn_mfma_f32_16x16x32_bf16(
                    aq[ks], bk, sc[nf], 0, 0, 0);
            }
        }
        __builtin_amdgcn_s_setprio(0);

        // scale + causal mask (diagonal tile only) + row max
        const bool needmask = (t == qt);
        float sv[4][4], mrow[4];
        #pragma unroll
        for (int r = 0; r < 4; ++r) {
            const int qglob = qbase + lg * 4 + r;
            #pragma unroll
            for (int nf = 0; nf < 4; ++nf) {
                float s = sc[nf][r] * SCALE2;
                if (needmask && (t * 64 + nf * 16 + lr > qglob)) s = -3e38f;
                sv[r][nf] = s;
            }
            float mr = fmaxf(fmaxf(sv[r][0], sv[r][1]),
                             fmaxf(sv[r][2], sv[r][3]));
            #pragma unroll
            for (int o = 1; o < 16; o <<= 1)
                mr = fmaxf(mr, __shfl_xor(mr, o));
            mrow[r] = mr;
        }

        // defer-max: wave-uniform skip of the rescale pass
        bool grow = false;
        #pragma unroll
        for (int r = 0; r < 4; ++r) grow |= (mrow[r] > mreg[r] + THR);

        if (__any(grow)) {
            #pragma unroll
            for (int r = 0; r < 4; ++r) {
                float mnew = fmaxf(mreg[r], mrow[r]);
                float cf = exp2f(mreg[r] - mnew);
                mreg[r] = mnew;
                float ps = 0.f;
                #pragma unroll
                for (int nf = 0; nf < 4; ++nf) {
                    float p = exp2f(sv[r][nf] - mnew);
                    ps += p;
                    Pl[wv][lg * 4 + r][nf * 16 + lr] = (short)f2b(p);
                }
                #pragma unroll
                for (int o = 1; o < 16; o <<= 1)
                    ps += __shfl_xor(ps, o);
                lreg[r] = lreg[r] * cf + ps;
                #pragma unroll
                for (int nf = 0; nf < 4; ++nf) oacc[nf][r] *= cf;
            }
        } else {
            #pragma unroll
            for (int r = 0; r < 4; ++r) {
                float ps = 0.f;
                #pragma unroll
                for (int nf = 0; nf < 4; ++nf) {
                    float p = exp2f(sv[r][nf] - mreg[r]);
                    ps += p;
                    Pl[wv][lg * 4 + r][nf * 16 + lr] = (short)f2b(p);
                }
                #pragma unroll
                for (int o = 1; o < 16; o <<= 1)
                    ps += __shfl_xor(ps, o);
                lreg[r] += ps;
            }
        }

        // P is wave-local: order LDS writes before reads without block barrier
        asm volatile("s_waitcnt lgkmcnt(0)" ::: "memory");
        __builtin_amdgcn_sched_barrier(0);

        // PV: O[16 q][64 d] += P @ V
        __builtin_amdgcn_s_setprio(1);
        #pragma unroll
        for (int ks = 0; ks < 2; ++ks) {
            short8 pa = *(const short8*)&Pl[wv][lr][ks * 32 + lg * 8];
            #pragma unroll
            for (int nf = 0; nf < 4; ++nf) {
                short8 bv8 = *(const short8*)&Vtl[nf * 16 + lr][ks * 32 + lg * 8];
                oacc[nf] = __builtin_amdgcn_mfma_f32_16x16x32_bf16(
                    pa, bv8, oacc[nf], 0, 0, 0);
            }
        }
        __builtin_amdgcn_s_setprio(0);
    }

    // normalize + write ctx [B,S,D] bf16
    #pragma unroll
    for (int r = 0; r < 4; ++r) {
        float inv = 1.0f / lreg[r];
        int q = qbase + lg * 4 + r;
        size_t o = ((size_t)b * Sq + q) * Dm + h * HDm;
        #pragma unroll
        for (int nf = 0; nf < 4; ++nf)
            ctx[o + nf * 16 + lr] = (short)f2b(oacc[nf][r] * inv);
    }
}

// ---------------------------------------------------------------------------
// Row LayerNorm: block per row (1024), 256 thr x float4. Optional bf16 copy.
// ---------------------------------------------------------------------------
template<int BF16OUT>
__global__ __launch_bounds__(256) void ln_kernel(
    const float* __restrict__ in, const float* __restrict__ g,
    const float* __restrict__ be, float* __restrict__ outf,
    short* __restrict__ outb)
{
    const int m = blockIdx.x;
    const int tid = threadIdx.x;
    const float4 vl = *(const float4*)&in[(size_t)m * Dm + tid * 4];
    float s  = vl.x + vl.y + vl.z + vl.w;
    float s2 = vl.x * vl.x + vl.y * vl.y + vl.z * vl.z + vl.w * vl.w;
    #pragma unroll
    for (int o = 32; o > 0; o >>= 1) {
        s  += __shfl_down(s, o);
        s2 += __shfl_down(s2, o);
    }
    __shared__ float rs[4], rs2[4];
    const int w = tid >> 6;
    if ((tid & 63) == 0) { rs[w] = s; rs2[w] = s2; }
    __syncthreads();
    s  = rs[0] + rs[1] + rs[2] + rs[3];
    s2 = rs2[0] + rs2[1] + rs2[2] + rs2[3];
    const float mean = s * (1.0f / Dm);
    const float var  = s2 * (1.0f / Dm) - mean * mean;
    const float rstd = rsqrtf(var + 1e-5f);
    const float4 gv = *(const float4*)&g[tid * 4];
    const float4 bv = *(const float4*)&be[tid * 4];
    float4 ov;
    ov.x = (vl.x - mean) * rstd * gv.x + bv.x;
    ov.y = (vl.y - mean) * rstd * gv.y + bv.y;
    ov.z = (vl.z - mean) * rstd * gv.z + bv.z;
    ov.w = (vl.w - mean) * rstd * gv.w + bv.w;
    *(float4*)&outf[(size_t)m * Dm + tid * 4] = ov;
    if (BF16OUT) {
        short4v o4;
        o4[0] = (short)f2b(ov.x); o4[1] = (short)f2b(ov.y);
        o4[2] = (short)f2b(ov.z); o4[3] = (short)f2b(ov.w);
        *(short4v*)&outb[(size_t)m * Dm + tid * 4] = o4;
    }
}

// ---------------------------------------------------------------------------
extern "C" void kernel_launch(void* const* d_in, const int* in_sizes, int n_in,
                              void* d_out, int out_size, void* d_ws, size_t ws_size,
                              hipStream_t stream)
{
    const float* x  = (const float*)d_in[0];
    const float* Wq = (const float*)d_in[1];
    const float* bq = (const float*)d_in[2];
    const float* Wk = (const float*)d_in[3];
    const float* bk = (const float*)d_in[4];
    const float* Wv = (const float*)d_in[5];
    const float* bv = (const float*)d_in[6];
    const float* Wo = (const float*)d_in[7];
    const float* bo = (const float*)d_in[8];
    const float* W1 = (const float*)d_in[9];
    const float* b1 = (const float*)d_in[10];
    const float* W2 = (const float*)d_in[11];
    const float* b2 = (const float*)d_in[12];
    const float* g1 = (const float*)d_in[13];
    const float* be1= (const float*)d_in[14];
    const float* g2 = (const float*)d_in[15];
    const float* be2= (const float*)d_in[16];
    float* out = (float*)d_out;

    char* ws = (char*)d_ws;
    size_t off = 0;
    auto alloc = [&](size_t bytes) {
        char* p = ws + off;
        off += (bytes + 255) & ~(size_t)255;
        return p;
    };
    const size_t MD2 = (size_t)Mm * Dm * 2;          // 8 MB
    short* xb    = (short*)alloc(MD2);
    short* wqkvt = (short*)alloc((size_t)3072 * Dm * 2);
    float* bcat  = (float*)alloc(3072 * 4);
    short* wot   = (short*)alloc((size_t)Dm * Dm * 2);
    short* w1t   = (short*)alloc((size_t)FFm * Dm * 2);
    short* w2t   = (short*)alloc((size_t)Dm * FFm * 2);
    short* qb    = (short*)alloc(MD2);
    short* kb    = (short*)alloc(MD2);
    short* vb    = (short*)alloc(MD2);
    short* ctxb  = (short*)alloc(MD2);
    short* hb    = qb;                                // alias: q/k/v/ctx dead by FF1
    float* y     = (float*)alloc((size_t)Mm * Dm * 4);
    float* x1f   = (float*)alloc((size_t)Mm * Dm * 4);
    short* x1b   = (short*)alloc(MD2);
    float* y2    = y;                                 // alias: y dead after LN1
    short* vtb   = (short*)y;                         // alias: vtb dead before Wo-gemm writes y

    // --- weight/activation prep (bf16, transposed) ---
    convert_x<<<Mm * Dm / 1024, 256, 0, stream>>>(x, xb);
    build_wqkv<<<dim3(16, 16, 3), 256, 0, stream>>>(Wq, Wk, Wv, wqkvt);
    build_bqkv<<<12, 256, 0, stream>>>(bq, bk, bv, bcat);
    transpose_to_bf16<<<dim3(16, 16), 256, 0, stream>>>(Wo, wot, Dm, Dm);
    transpose_to_bf16<<<dim3(64, 16), 256, 0, stream>>>(W1, w1t, Dm, FFm);
    transpose_to_bf16<<<dim3(16, 64), 256, 0, stream>>>(W2, w2t, FFm, Dm);

    // --- decoder layer ---
    gemm_bf16<2, 128><<<dim3(32, 24), 256, 0, stream>>>(
        xb, wqkvt, bcat, nullptr, nullptr, nullptr, qb, kb, vb, Dm, 3072);
    transpose_v<<<dim3(32, 32), 256, 0, stream>>>(vb, vtb);
    attn_mfma<<<1024, 256, 0, stream>>>(qb, kb, vtb, ctxb);
    gemm_bf16<0, 64><<<dim3(64, 8), 256, 0, stream>>>(
        ctxb, wot, bo, x, y, nullptr, nullptr, nullptr, nullptr, Dm, Dm);
    ln_kernel<1><<<Mm, 256, 0, stream>>>(y, g1, be1, x1f, x1b);
    gemm_bf16<1, 128><<<dim3(32, 32), 256, 0, stream>>>(
        x1b, w1t, b1, nullptr, nullptr, hb, nullptr, nullptr, nullptr, Dm, FFm);
    gemm_bf16<0, 64><<<dim3(64, 8), 256, 0, stream>>>(
        hb, w2t, b2, x1f, y2, nullptr, nullptr, nullptr, nullptr, FFm, Dm);
    ln_kernel<0><<<Mm, 256, 0, stream>>>(y2, g2, be2, out, nullptr);
}